// Round 10
// baseline (320.276 us; speedup 1.0000x reference)
//
#include <hip/hip_runtime.h>
#include <hip/hip_fp16.h>

// GAT 2-layer forward, MI355X. N=100000, E=1.6M (+N self-loops), Fin=128,
// H=8, C=16 (H*C=128), Fout=64, 256 graphs.
//
// Round 10: (a) banded CSR — neighbor lists approx-ordered by src>>13 so
// concurrent gather blocks sweep xl in ~2MB bands (L2-resident) instead of
// randomly; (b) merged convWT+hist, scanB folded into scanC; (c) es/ed
// pre-scaled by log2(e), gathers use exp2f.

#define LRELU_SLOPE 0.2f
#define NBLKB 512          // bucketing blocks
#define NBUCK 256          // buckets (dst>>9, N<=131072)
#define LOG2E 1.4426950408889634f

__device__ __forceinline__ float lrelu(float x) { return x > 0.f ? x : LRELU_SLOPE * x; }

typedef _Float16 f16x8 __attribute__((ext_vector_type(8)));
typedef float f32x4 __attribute__((ext_vector_type(4)));

// ---------------- MFMA GEMM + fused attention scalars -----------------------
// A-frag: lane holds A[row=l&15][k=(l>>4)*8+j]; B-frag: B[k][col=l&15];
// D: D[row=(l>>4)*4+j][col=l&15]  (verified m89 mapping).
// es/ed stored pre-multiplied by log2(e) (gathers use exp2f; lrelu commutes
// with positive scaling).
template<typename TX, int M_, int HEADS>
__global__ __launch_bounds__(256) void gemm_mfma(const TX* __restrict__ X,
    const __half* __restrict__ Wt, __half* __restrict__ Y,
    const float* __restrict__ as, const float* __restrict__ ad,
    float* __restrict__ es, float* __restrict__ ed, int N) {
  constexpr int K = 128;
  constexpr int BM = 64;
  constexpr int LP = K + 8;                 // LDS pitch in halves (272B rows)
  __shared__ _Float16 Xl[BM * LP];
  const int tid = threadIdx.x;
  const int row0 = blockIdx.x * BM;

  if constexpr (sizeof(TX) == 4) {          // f32 input -> convert
    for (int i = tid; i < BM * (K / 4); i += 256) {
      const int r = i / (K / 4), c4 = (i % (K / 4)) * 4;
      int gr = row0 + r; if (gr >= N) gr = N - 1;
      const float4 v = *(const float4*)((const float*)X + (size_t)gr * K + c4);
      _Float16* d = &Xl[r * LP + c4];
      d[0] = (_Float16)v.x; d[1] = (_Float16)v.y;
      d[2] = (_Float16)v.z; d[3] = (_Float16)v.w;
    }
  } else {                                  // f16 input
    for (int i = tid; i < BM * (K / 8); i += 256) {
      const int r = i / (K / 8), c8 = (i % (K / 8)) * 8;
      int gr = row0 + r; if (gr >= N) gr = N - 1;
      const f16x8 v = *(const f16x8*)((const _Float16*)X + (size_t)gr * K + c8);
      *(f16x8*)&Xl[r * LP + c8] = v;
    }
  }
  __syncthreads();

  const int w = tid >> 6, l = tid & 63;
  const int lrow = l & 15, lk = (l >> 4) * 8;
  constexpr int NT = M_ / 16;
  f32x4 acc[NT];
#pragma unroll
  for (int n = 0; n < NT; ++n) acc[n] = (f32x4){0.f, 0.f, 0.f, 0.f};

#pragma unroll
  for (int kk = 0; kk < K; kk += 32) {
    const f16x8 a = *(const f16x8*)&Xl[(w * 16 + lrow) * LP + kk + lk];
#pragma unroll
    for (int n = 0; n < NT; ++n) {
      const f16x8 b = *(const f16x8*)((const _Float16*)Wt +
                        (size_t)(n * 16 + lrow) * K + kk + lk);
      acc[n] = __builtin_amdgcn_mfma_f32_16x16x32_f16(a, b, acc[n], 0, 0, 0);
    }
  }
  const int orow = row0 + w * 16 + (l >> 4) * 4;
#pragma unroll
  for (int n = 0; n < NT; ++n) {
#pragma unroll
    for (int j = 0; j < 4; ++j) {
      const int gr = orow + j;
      if (gr < N) Y[(size_t)gr * M_ + n * 16 + lrow] = __float2half(acc[n][j]);
    }
  }

  // fused attention scalars (pre-scaled by log2 e)
  if constexpr (HEADS == 8) {
#pragma unroll
    for (int n = 0; n < NT; ++n) {
#pragma unroll
      for (int j = 0; j < 4; ++j) {
        float ps = acc[n][j] * as[n * 16 + lrow];
        float pd = acc[n][j] * ad[n * 16 + lrow];
#pragma unroll
        for (int o = 1; o <= 8; o <<= 1) {
          ps += __shfl_xor(ps, o);
          pd += __shfl_xor(pd, o);
        }
        if (lrow == n) {
          const int gr = orow + j;
          if (gr < N) { es[gr * 8 + n] = ps * LOG2E; ed[gr * 8 + n] = pd * LOG2E; }
        }
      }
    }
  } else {
#pragma unroll
    for (int j = 0; j < 4; ++j) {
      float ps = 0.f, pd = 0.f;
#pragma unroll
      for (int n = 0; n < NT; ++n) {
        ps += acc[n][j] * as[n * 16 + lrow];
        pd += acc[n][j] * ad[n * 16 + lrow];
      }
#pragma unroll
      for (int o = 1; o <= 8; o <<= 1) {
        ps += __shfl_xor(ps, o);
        pd += __shfl_xor(pd, o);
      }
      if (lrow == 0) {
        const int gr = orow + j;
        if (gr < N) { es[gr] = ps * LOG2E; ed[gr] = pd * LOG2E; }
      }
    }
  }
}

// ---------------- CSR build: LDS counting sort (packed records) -------------
// fused: blocks [0,NBLKB) do the bucket histogram; blocks [NBLKB,+24) convert
// W1/W2 to f16-transposed.
__global__ __launch_bounds__(1024) void hist_conv(const int* __restrict__ ei, int E,
    int* __restrict__ bh, const float* __restrict__ W1, const float* __restrict__ W2,
    __half* __restrict__ Wt1, __half* __restrict__ Wt2) {
  const int t = threadIdx.x;
  if (blockIdx.x < NBLKB) {
    __shared__ int hist[NBUCK];
    if (t < NBUCK) hist[t] = 0;
    __syncthreads();
    const int chunk = (E + NBLKB - 1) / NBLKB;
    const int s0 = blockIdx.x * chunk;
    const int s1 = min(E, s0 + chunk);
    for (int e = s0 + t; e < s1; e += 1024) atomicAdd(&hist[ei[E + e] >> 9], 1);
    __syncthreads();
    if (t < NBUCK) bh[t * NBLKB + blockIdx.x] = hist[t];
  } else {
    const int i = (blockIdx.x - NBLKB) * 1024 + t;
    if (i < 128 * 128) {
      const int k = i >> 7, m = i & 127;
      Wt1[m * 128 + k] = __float2half(W1[i]);
    } else if (i < 128 * 128 + 128 * 64) {
      const int j = i - 128 * 128;
      const int k = j >> 6, m = j & 63;
      Wt2[m * 128 + k] = __float2half(W2[j]);
    }
  }
}

__global__ __launch_bounds__(256) void scanA(int* __restrict__ a, int* __restrict__ ctot, int N) {
  __shared__ int sm[256];
  const int base = blockIdx.x * 1024;
  const int t = threadIdx.x;
  int v[4], s = 0;
#pragma unroll
  for (int i = 0; i < 4; ++i) {
    const int idx = base + t * 4 + i;
    v[i] = (idx < N) ? a[idx] : 0;
    s += v[i];
  }
  sm[t] = s;
  __syncthreads();
  for (int o = 1; o < 256; o <<= 1) {
    const int x = (t >= o) ? sm[t - o] : 0;
    __syncthreads();
    sm[t] += x;
    __syncthreads();
  }
  if (t == 255) ctot[blockIdx.x] = sm[255];
  int run = sm[t] - s;
#pragma unroll
  for (int i = 0; i < 4; ++i) {
    const int idx = base + t * 4 + i;
    if (idx < N) a[idx] = run;
    run += v[i];
  }
}

// scanC with inline scan of the 128-entry ctot (scanB eliminated)
__global__ __launch_bounds__(256) void scanC(int* __restrict__ a,
    const int* __restrict__ ctot, int NCH, int Ntot) {
  __shared__ int sc[128];
  const int t = threadIdx.x;
  if (t < 128) sc[t] = (t < NCH) ? ctot[t] : 0;
  __syncthreads();
  for (int o = 1; o < 128; o <<= 1) {
    int x = 0;
    if (t < 128 && t >= o) x = sc[t - o];
    __syncthreads();
    if (t < 128) sc[t] += x;
    __syncthreads();
  }
  const int i = blockIdx.x * 256 + t;
  if (i < Ntot) {
    const int c = i >> 10;
    a[i] += (c == 0) ? 0 : sc[c - 1];
  }
}

__global__ __launch_bounds__(1024) void bucket_scatter(const int* __restrict__ ei, int E,
    const int* __restrict__ bh, int* __restrict__ eb) {
  __shared__ int offs[NBUCK];
  const int t = threadIdx.x;
  if (t < NBUCK) offs[t] = bh[t * NBLKB + blockIdx.x];
  __syncthreads();
  const int chunk = (E + NBLKB - 1) / NBLKB;
  const int s0 = blockIdx.x * chunk;
  const int s1 = min(E, s0 + chunk);
  for (int e = s0 + t; e < s1; e += 1024) {
    const int s = ei[e], d = ei[E + e];
    const int pos = atomicAdd(&offs[d >> 9], 1);
    eb[pos] = (s << 9) | (d & 511);
  }
}

// per-bucket finalize: rowptr[n] = END of node n (start = rowptr[n-1]).
// Scatter in src-band passes (src>>13, ~2MB of xl per band) so each node's
// list is approximately band-ordered -> gather blocks sweep xl in bands.
__global__ __launch_bounds__(512) void csr_bucket(const int* __restrict__ eb,
    const int* __restrict__ bh, int E, int N,
    int* __restrict__ rowptr, int* __restrict__ csr) {
  __shared__ int deg[512];
  __shared__ int sm[512];
  const int t = threadIdx.x;
  const int bucket = blockIdx.x;
  const int bstart = bh[bucket * NBLKB];
  const int bend = (bucket + 1 < NBUCK) ? bh[(bucket + 1) * NBLKB] : E;
  const int n0 = bucket << 9;
  deg[t] = 0;
  __syncthreads();
  for (int j = bstart + t; j < bend; j += 512) atomicAdd(&deg[eb[j] & 511], 1);
  __syncthreads();
  const int v = deg[t];
  sm[t] = v;
  __syncthreads();
  for (int o = 1; o < 512; o <<= 1) {
    const int x = (t >= o) ? sm[t - o] : 0;
    __syncthreads();
    sm[t] += x;
    __syncthreads();
  }
  if (n0 + t < N) rowptr[n0 + t] = bstart + sm[t];
  deg[t] = bstart + sm[t] - v;          // start slot for scatter
  __syncthreads();
  const int nband = (N + 8191) >> 13;   // src bands of 8192 nodes
  for (int b = 0; b < nband; ++b) {
    for (int j = bstart + t; j < bend; j += 512) {
      const int e = eb[j];
      if ((e >> 22) == b) {             // src band = (e>>9)>>13
        const int pos = atomicAdd(&deg[e & 511], 1);
        csr[pos] = e >> 9;
      }
    }
  }
}

// ---------------- layer-1 gather: 2 edges/wave, 32 lanes x 4ch each ---------
__global__ __launch_bounds__(256) void gather_h8(const __half* __restrict__ xl,
    const float* __restrict__ es, const float* __restrict__ ed,
    const int* __restrict__ rowptr, const int* __restrict__ csr,
    const float* __restrict__ bias, __half* __restrict__ hout, int N) {
  const int wave = threadIdx.x >> 6, lane = threadIdx.x & 63;
  const int n = blockIdx.x * 4 + wave;
  if (n >= N) return;
  const int sub = lane >> 5;       // which edge of the pair
  const int sl  = lane & 31;       // channels 4sl..4sl+3
  const int c0  = sl * 4;
  const int h   = sl >> 2;
  const float edv = ed[n * 8 + h];
  const int start = (n == 0) ? 0 : rowptr[n - 1];
  const int end   = rowptr[n];
  union U8 { uint2 u; __half2 h2[2]; };

  float4 acc = make_float4(0.f, 0.f, 0.f, 0.f);
  float ssum = 0.f;
  if (sub == 0) {    // self loop
    const float ee = exp2f(lrelu(es[n * 8 + h] + edv));
    U8 r; r.u = *(const uint2*)&xl[(size_t)n * 128 + c0];
    const float2 f0 = __half22float2(r.h2[0]), f1 = __half22float2(r.h2[1]);
    acc.x = ee * f0.x; acc.y = ee * f0.y; acc.z = ee * f1.x; acc.w = ee * f1.y;
    ssum = ee;
  }
  int j = start + sub;
  for (; j + 6 < end; j += 8) {    // 4 edges per sub per trip (8/wave)
    int s0 = csr[j], s1 = csr[j + 2], s2 = csr[j + 4], s3 = csr[j + 6];
    float ev[4]; U8 r[4];
    ev[0] = es[s0 * 8 + h]; r[0].u = *(const uint2*)&xl[(size_t)s0 * 128 + c0];
    ev[1] = es[s1 * 8 + h]; r[1].u = *(const uint2*)&xl[(size_t)s1 * 128 + c0];
    ev[2] = es[s2 * 8 + h]; r[2].u = *(const uint2*)&xl[(size_t)s2 * 128 + c0];
    ev[3] = es[s3 * 8 + h]; r[3].u = *(const uint2*)&xl[(size_t)s3 * 128 + c0];
#pragma unroll
    for (int k = 0; k < 4; ++k) {
      const float ee = exp2f(lrelu(ev[k] + edv));
      const float2 f0 = __half22float2(r[k].h2[0]), f1 = __half22float2(r[k].h2[1]);
      acc.x += ee * f0.x; acc.y += ee * f0.y;
      acc.z += ee * f1.x; acc.w += ee * f1.y;
      ssum += ee;
    }
  }
  for (; j < end; j += 2) {
    const int src = csr[j];
    const float ee = exp2f(lrelu(es[src * 8 + h] + edv));
    U8 r; r.u = *(const uint2*)&xl[(size_t)src * 128 + c0];
    const float2 f0 = __half22float2(r.h2[0]), f1 = __half22float2(r.h2[1]);
    acc.x += ee * f0.x; acc.y += ee * f0.y;
    acc.z += ee * f1.x; acc.w += ee * f1.y;
    ssum += ee;
  }
  acc.x += __shfl_xor(acc.x, 32); acc.y += __shfl_xor(acc.y, 32);
  acc.z += __shfl_xor(acc.z, 32); acc.w += __shfl_xor(acc.w, 32);
  ssum  += __shfl_xor(ssum, 32);
  if (sub == 0) {
    const float inv = 1.f / (ssum + 1e-16f);
    const float4 b4 = *(const float4*)&bias[c0];
    float v0 = acc.x * inv + b4.x, v1 = acc.y * inv + b4.y;
    float v2 = acc.z * inv + b4.z, v3 = acc.w * inv + b4.w;
    v0 = v0 > 0.f ? v0 : __expf(v0) - 1.f;
    v1 = v1 > 0.f ? v1 : __expf(v1) - 1.f;
    v2 = v2 > 0.f ? v2 : __expf(v2) - 1.f;
    v3 = v3 > 0.f ? v3 : __expf(v3) - 1.f;
    U8 o; o.h2[0] = __floats2half2_rn(v0, v1); o.h2[1] = __floats2half2_rn(v2, v3);
    *(uint2*)&hout[(size_t)n * 128 + c0] = o.u;
  }
}

// ---------------- layer-2 gather: 4 edges/wave, 16 lanes x 4ch each ---------
__global__ __launch_bounds__(256) void gather_h1(const __half* __restrict__ xl2,
    const float* __restrict__ es, const float* __restrict__ ed,
    const int* __restrict__ rowptr, const int* __restrict__ csr,
    const float* __restrict__ bias, float* __restrict__ vout, int N) {
  const int wave = threadIdx.x >> 6, lane = threadIdx.x & 63;
  const int n = blockIdx.x * 4 + wave;
  if (n >= N) return;
  const int sub = lane >> 4;       // 0..3
  const int sl  = lane & 15;       // channels 4sl..4sl+3
  const int c0  = sl * 4;
  const float edv = ed[n];
  const int start = (n == 0) ? 0 : rowptr[n - 1];
  const int end   = rowptr[n];
  union U8 { uint2 u; __half2 h2[2]; };

  float4 acc = make_float4(0.f, 0.f, 0.f, 0.f);
  float ssum = 0.f;
  if (sub == 0) {    // self loop
    const float ee = exp2f(lrelu(es[n] + edv));
    U8 r; r.u = *(const uint2*)&xl2[(size_t)n * 64 + c0];
    const float2 f0 = __half22float2(r.h2[0]), f1 = __half22float2(r.h2[1]);
    acc.x = ee * f0.x; acc.y = ee * f0.y; acc.z = ee * f1.x; acc.w = ee * f1.y;
    ssum = ee;
  }
  int j = start + sub;
  for (; j + 4 < end; j += 8) {    // 2 edges per sub per trip (8/wave)
    const int s0 = csr[j], s1 = csr[j + 4];
    const float e0 = es[s0], e1 = es[s1];
    U8 r0, r1;
    r0.u = *(const uint2*)&xl2[(size_t)s0 * 64 + c0];
    r1.u = *(const uint2*)&xl2[(size_t)s1 * 64 + c0];
    {
      const float ee = exp2f(lrelu(e0 + edv));
      const float2 f0 = __half22float2(r0.h2[0]), f1 = __half22float2(r0.h2[1]);
      acc.x += ee * f0.x; acc.y += ee * f0.y;
      acc.z += ee * f1.x; acc.w += ee * f1.y; ssum += ee;
    }
    {
      const float ee = exp2f(lrelu(e1 + edv));
      const float2 f0 = __half22float2(r1.h2[0]), f1 = __half22float2(r1.h2[1]);
      acc.x += ee * f0.x; acc.y += ee * f0.y;
      acc.z += ee * f1.x; acc.w += ee * f1.y; ssum += ee;
    }
  }
  for (; j < end; j += 4) {
    const int src = csr[j];
    const float ee = exp2f(lrelu(es[src] + edv));
    U8 r; r.u = *(const uint2*)&xl2[(size_t)src * 64 + c0];
    const float2 f0 = __half22float2(r.h2[0]), f1 = __half22float2(r.h2[1]);
    acc.x += ee * f0.x; acc.y += ee * f0.y;
    acc.z += ee * f1.x; acc.w += ee * f1.y; ssum += ee;
  }
#pragma unroll
  for (int o = 16; o <= 32; o <<= 1) {
    acc.x += __shfl_xor(acc.x, o); acc.y += __shfl_xor(acc.y, o);
    acc.z += __shfl_xor(acc.z, o); acc.w += __shfl_xor(acc.w, o);
    ssum  += __shfl_xor(ssum, o);
  }
  if (sub == 0) {
    const float inv = 1.f / (ssum + 1e-16f);
    const float4 b4 = *(const float4*)&bias[c0];
    float4 o;
    o.x = acc.x * inv + b4.x; o.y = acc.y * inv + b4.y;
    o.z = acc.z * inv + b4.z; o.w = acc.w * inv + b4.w;
    *(float4*)&vout[(size_t)n * 64 + c0] = o;
  }
}

// ---------------- segmented mean pool: 1 block per graph --------------------
__global__ __launch_bounds__(256) void pool_seg(const float* __restrict__ v,
    const int* __restrict__ batch, float* __restrict__ out, int N) {
  const int g = blockIdx.x;
  const int t = threadIdx.x;
  int lo = 0, hi = N;
  while (lo < hi) { const int m = (lo + hi) >> 1; if (batch[m] < g) lo = m + 1; else hi = m; }
  const int start = lo;
  hi = N;
  while (lo < hi) { const int m = (lo + hi) >> 1; if (batch[m] <= g) lo = m + 1; else hi = m; }
  const int end = lo;

  const int c = t & 63, rg = t >> 6;
  float s = 0.f;
  for (int r = start + rg; r < end; r += 4) s += v[(size_t)r * 64 + c];
  __shared__ float sm[256];
  sm[t] = s;
  __syncthreads();
  if (t < 64) {
    const float tot = sm[t] + sm[t + 64] + sm[t + 128] + sm[t + 192];
    out[g * 64 + t] = tot / fmaxf((float)(end - start), 1.f);
  }
}

extern "C" void kernel_launch(void* const* d_in, const int* in_sizes, int n_in,
                              void* d_out, int out_size, void* d_ws, size_t ws_size,
                              hipStream_t stream) {
  const float* x   = (const float*)d_in[0];
  const float* W1  = (const float*)d_in[1];
  const float* as1 = (const float*)d_in[2];
  const float* ad1 = (const float*)d_in[3];
  const float* b1  = (const float*)d_in[4];
  const float* W2  = (const float*)d_in[5];
  const float* as2 = (const float*)d_in[6];
  const float* ad2 = (const float*)d_in[7];
  const float* b2  = (const float*)d_in[8];
  const int* ei    = (const int*)d_in[9];
  const int* batch = (const int*)d_in[10];
  float* out = (float*)d_out;
  const int N = in_sizes[10];      // 100000
  const int E = in_sizes[9] / 2;   // 1600000
  const int G = out_size / 64;     // 256 graphs
  const int BH = NBUCK * NBLKB;    // 131072

  // workspace layout (bytes), with reuse:
  char* ws = (char*)d_ws;
  __half* xl  = (__half*)ws;                         // [N*128] f16
  __half* h   = (__half*)(ws + (size_t)N * 256);     // [N*128] f16
  __half* xl2 = xl;                                  // [N*64] f16 (xl dead)
  float* vbuf = (float*)(ws + (size_t)N * 256);      // [N*64] f32 (h dead)
  float* es1  = (float*)(ws + (size_t)N * 512);      // [N*8]
  float* ed1  = es1 + (size_t)N * 8;                 // [N*8]
  float* es2  = es1;                                 // [N]
  float* ed2  = es1 + N;                             // [N]
  int* rowptr = (int*)(ed1 + (size_t)N * 8);         // [N]
  int* csr    = rowptr + N;                          // [E]
  int* eb     = csr + E;                             // [E] packed (src<<9|dstlo)
  int* bh     = eb + E;                              // [131072]
  int* ctot   = bh + BH;                             // [128]
  __half* Wt1 = (__half*)((((uintptr_t)(ctot + 128)) + 31) & ~(uintptr_t)31); // [128*128]
  __half* Wt2 = Wt1 + 128 * 128;                     // [64*128]

  // ---- CSR build (bucket hist fused with W convert) ----
  hist_conv<<<NBLKB + 24, 1024, 0, stream>>>(ei, E, bh, W1, W2, Wt1, Wt2);
  scanA<<<BH / 1024, 256, 0, stream>>>(bh, ctot, BH);
  scanC<<<BH / 256, 256, 0, stream>>>(bh, ctot, BH / 1024, BH);
  bucket_scatter<<<NBLKB, 1024, 0, stream>>>(ei, E, bh, eb);
  csr_bucket<<<(N + 511) / 512, 512, 0, stream>>>(eb, bh, E, N, rowptr, csr);

  // ---- layer 1 (GEMM + fused att scalars) ----
  gemm_mfma<float, 128, 8><<<(N + 63) / 64, 256, 0, stream>>>(x, Wt1, xl, as1, ad1, es1, ed1, N);
  gather_h8<<<(N + 3) / 4, 256, 0, stream>>>(xl, es1, ed1, rowptr, csr, b1, h, N);

  // ---- layer 2 (GEMM + fused att scalars) ----
  gemm_mfma<__half, 64, 1><<<(N + 63) / 64, 256, 0, stream>>>(h, Wt2, xl2, as2, ad2, es2, ed2, N);
  gather_h1<<<(N + 3) / 4, 256, 0, stream>>>(xl2, es2, ed2, rowptr, csr, b2, vbuf, N);

  // ---- global mean pool (segmented, no atomics) ----
  pool_seg<<<G, 256, 0, stream>>>(vbuf, batch, out, N);
}

// Round 11
// 269.486 us; speedup vs baseline: 1.1885x; 1.1885x over previous
//
#include <hip/hip_runtime.h>
#include <hip/hip_fp16.h>

// GAT 2-layer forward, MI355X. N=100000, E=1.6M (+N self-loops), Fin=128,
// H=8, C=16 (H*C=128), Fout=64, 256 graphs.
//
// Round 11: revert r10 banding (FETCH unchanged -> theory wrong; 13-pass
// rescatter cost 33us). Keep hist+convWT fusion, scanB-fold, exp2f. New:
// (a) csr_bucket fused with gemm1 into one 512-thr launch (independent ops
// run concurrently instead of serialized); (b) gather_h8 as 4 edges/wave x
// 16 lanes x 8ch (halves per-edge scalar VALU, bytes unchanged).

#define LRELU_SLOPE 0.2f
#define NBLKB 512          // bucketing blocks
#define NBUCK 256          // buckets (dst>>9, N<=131072)
#define LOG2E 1.4426950408889634f

__device__ __forceinline__ float lrelu(float x) { return x > 0.f ? x : LRELU_SLOPE * x; }

typedef _Float16 f16x8 __attribute__((ext_vector_type(8)));
typedef float f32x4 __attribute__((ext_vector_type(4)));

// ---------------- K1: bucket histogram + W1/W2 convert-transpose ------------
__global__ __launch_bounds__(1024) void hist_conv(const int* __restrict__ ei, int E,
    int* __restrict__ bh, const float* __restrict__ W1, const float* __restrict__ W2,
    __half* __restrict__ Wt1, __half* __restrict__ Wt2) {
  const int t = threadIdx.x;
  if (blockIdx.x < NBLKB) {
    __shared__ int hist[NBUCK];
    if (t < NBUCK) hist[t] = 0;
    __syncthreads();
    const int chunk = (E + NBLKB - 1) / NBLKB;
    const int s0 = blockIdx.x * chunk;
    const int s1 = min(E, s0 + chunk);
    for (int e = s0 + t; e < s1; e += 1024) atomicAdd(&hist[ei[E + e] >> 9], 1);
    __syncthreads();
    if (t < NBUCK) bh[t * NBLKB + blockIdx.x] = hist[t];
  } else {
    const int i = (blockIdx.x - NBLKB) * 1024 + t;
    if (i < 128 * 128) {
      const int k = i >> 7, m = i & 127;
      Wt1[m * 128 + k] = __float2half(W1[i]);
    } else if (i < 128 * 128 + 128 * 64) {
      const int j = i - 128 * 128;
      const int k = j >> 6, m = j & 63;
      Wt2[m * 128 + k] = __float2half(W2[j]);
    }
  }
}

// ---------------- scans ------------------------------------------------------
__global__ __launch_bounds__(256) void scanA(int* __restrict__ a, int* __restrict__ ctot, int N) {
  __shared__ int sm[256];
  const int base = blockIdx.x * 1024;
  const int t = threadIdx.x;
  int v[4], s = 0;
#pragma unroll
  for (int i = 0; i < 4; ++i) {
    const int idx = base + t * 4 + i;
    v[i] = (idx < N) ? a[idx] : 0;
    s += v[i];
  }
  sm[t] = s;
  __syncthreads();
  for (int o = 1; o < 256; o <<= 1) {
    const int x = (t >= o) ? sm[t - o] : 0;
    __syncthreads();
    sm[t] += x;
    __syncthreads();
  }
  if (t == 255) ctot[blockIdx.x] = sm[255];
  int run = sm[t] - s;
#pragma unroll
  for (int i = 0; i < 4; ++i) {
    const int idx = base + t * 4 + i;
    if (idx < N) a[idx] = run;
    run += v[i];
  }
}

// scanC with inline scan of the 128-entry ctot
__global__ __launch_bounds__(256) void scanC(int* __restrict__ a,
    const int* __restrict__ ctot, int NCH, int Ntot) {
  __shared__ int sc[128];
  const int t = threadIdx.x;
  if (t < 128) sc[t] = (t < NCH) ? ctot[t] : 0;
  __syncthreads();
  for (int o = 1; o < 128; o <<= 1) {
    int x = 0;
    if (t < 128 && t >= o) x = sc[t - o];
    __syncthreads();
    if (t < 128) sc[t] += x;
    __syncthreads();
  }
  const int i = blockIdx.x * 256 + t;
  if (i < Ntot) {
    const int c = i >> 10;
    a[i] += (c == 0) ? 0 : sc[c - 1];
  }
}

// ---------------- K3: scatter into bucket-grouped packed records ------------
__global__ __launch_bounds__(1024) void bucket_scatter(const int* __restrict__ ei, int E,
    const int* __restrict__ bh, int* __restrict__ eb) {
  __shared__ int offs[NBUCK];
  const int t = threadIdx.x;
  if (t < NBUCK) offs[t] = bh[t * NBLKB + blockIdx.x];
  __syncthreads();
  const int chunk = (E + NBLKB - 1) / NBLKB;
  const int s0 = blockIdx.x * chunk;
  const int s1 = min(E, s0 + chunk);
  for (int e = s0 + t; e < s1; e += 1024) {
    const int s = ei[e], d = ei[E + e];
    const int pos = atomicAdd(&offs[d >> 9], 1);
    eb[pos] = (s << 9) | (d & 511);
  }
}

// ---------------- K4 fused: csr_bucket (blocks < nbCsr) | gemm1 (rest) ------
// csr part: per-bucket finalize, rowptr[n]=END of node n.
// gemm part: Y=X@Wt1^T in f16 MFMA, BM=128 (8 waves), + fused att scalars
// (pre-scaled by log2 e). D-frag mapping per verified m89 layout.
__global__ __launch_bounds__(512) void csrb_gemm1(
    const int* __restrict__ eb, const int* __restrict__ bh, int E,
    int* __restrict__ rowptr, int* __restrict__ csr, int nbCsr,
    const float* __restrict__ X, const __half* __restrict__ Wt,
    __half* __restrict__ Y, const float* __restrict__ as,
    const float* __restrict__ ad, float* __restrict__ es, float* __restrict__ ed,
    int N) {
  __shared__ union U {
    struct { int deg[512]; int sm[512]; } c;
    _Float16 xl[128 * 136];
  } u;
  const int t = threadIdx.x;

  if (blockIdx.x < nbCsr) {
    // ---- CSR bucket finalize ----
    const int bucket = blockIdx.x;
    const int bstart = bh[bucket * NBLKB];
    const int bend = (bucket + 1 < NBUCK) ? bh[(bucket + 1) * NBLKB] : E;
    const int n0 = bucket << 9;
    u.c.deg[t] = 0;
    __syncthreads();
    for (int j = bstart + t; j < bend; j += 512) atomicAdd(&u.c.deg[eb[j] & 511], 1);
    __syncthreads();
    const int v = u.c.deg[t];
    u.c.sm[t] = v;
    __syncthreads();
    for (int o = 1; o < 512; o <<= 1) {
      const int x = (t >= o) ? u.c.sm[t - o] : 0;
      __syncthreads();
      u.c.sm[t] += x;
      __syncthreads();
    }
    if (n0 + t < N) rowptr[n0 + t] = bstart + u.c.sm[t];
    u.c.deg[t] = bstart + u.c.sm[t] - v;   // start slot
    __syncthreads();
    for (int j = bstart + t; j < bend; j += 512) {
      const int e = eb[j];
      const int pos = atomicAdd(&u.c.deg[e & 511], 1);
      csr[pos] = e >> 9;
    }
  } else {
    // ---- MFMA GEMM, BM=128, 8 waves ----
    constexpr int K = 128, LP = 136, NT = 8;
    const int row0 = (blockIdx.x - nbCsr) * 128;
    for (int i = t; i < 128 * (K / 4); i += 512) {
      const int r = i / (K / 4), c4 = (i % (K / 4)) * 4;
      int gr = row0 + r; if (gr >= N) gr = N - 1;
      const float4 vv = *(const float4*)(X + (size_t)gr * K + c4);
      _Float16* d = &u.xl[r * LP + c4];
      d[0] = (_Float16)vv.x; d[1] = (_Float16)vv.y;
      d[2] = (_Float16)vv.z; d[3] = (_Float16)vv.w;
    }
    __syncthreads();

    const int w = t >> 6, l = t & 63;
    const int lrow = l & 15, lk = (l >> 4) * 8;
    f32x4 acc[NT];
#pragma unroll
    for (int n = 0; n < NT; ++n) acc[n] = (f32x4){0.f, 0.f, 0.f, 0.f};
#pragma unroll
    for (int kk = 0; kk < K; kk += 32) {
      const f16x8 a = *(const f16x8*)&u.xl[(w * 16 + lrow) * LP + kk + lk];
#pragma unroll
      for (int n = 0; n < NT; ++n) {
        const f16x8 b = *(const f16x8*)((const _Float16*)Wt +
                          (size_t)(n * 16 + lrow) * K + kk + lk);
        acc[n] = __builtin_amdgcn_mfma_f32_16x16x32_f16(a, b, acc[n], 0, 0, 0);
      }
    }
    const int orow = row0 + w * 16 + (l >> 4) * 4;
#pragma unroll
    for (int n = 0; n < NT; ++n) {
#pragma unroll
      for (int j = 0; j < 4; ++j) {
        const int gr = orow + j;
        if (gr < N) Y[(size_t)gr * 128 + n * 16 + lrow] = __float2half(acc[n][j]);
      }
    }
    // fused att scalars (H=8), pre-scaled by log2 e
#pragma unroll
    for (int n = 0; n < NT; ++n) {
#pragma unroll
      for (int j = 0; j < 4; ++j) {
        float ps = acc[n][j] * as[n * 16 + lrow];
        float pd = acc[n][j] * ad[n * 16 + lrow];
#pragma unroll
        for (int o = 1; o <= 8; o <<= 1) {
          ps += __shfl_xor(ps, o);
          pd += __shfl_xor(pd, o);
        }
        if (lrow == n) {
          const int gr = orow + j;
          if (gr < N) { es[gr * 8 + n] = ps * LOG2E; ed[gr * 8 + n] = pd * LOG2E; }
        }
      }
    }
  }
}

// ---------------- gemm2 (M=64, H=1), 256 threads ----------------------------
__global__ __launch_bounds__(256) void gemm2(const __half* __restrict__ X,
    const __half* __restrict__ Wt, __half* __restrict__ Y,
    const float* __restrict__ as, const float* __restrict__ ad,
    float* __restrict__ es, float* __restrict__ ed, int N) {
  constexpr int K = 128, BM = 64, LP = 136, NT = 4;
  __shared__ _Float16 Xl[BM * LP];
  const int tid = threadIdx.x;
  const int row0 = blockIdx.x * BM;
  for (int i = tid; i < BM * (K / 8); i += 256) {
    const int r = i / (K / 8), c8 = (i % (K / 8)) * 8;
    int gr = row0 + r; if (gr >= N) gr = N - 1;
    const f16x8 v = *(const f16x8*)((const _Float16*)X + (size_t)gr * K + c8);
    *(f16x8*)&Xl[r * LP + c8] = v;
  }
  __syncthreads();
  const int w = tid >> 6, l = tid & 63;
  const int lrow = l & 15, lk = (l >> 4) * 8;
  f32x4 acc[NT];
#pragma unroll
  for (int n = 0; n < NT; ++n) acc[n] = (f32x4){0.f, 0.f, 0.f, 0.f};
#pragma unroll
  for (int kk = 0; kk < K; kk += 32) {
    const f16x8 a = *(const f16x8*)&Xl[(w * 16 + lrow) * LP + kk + lk];
#pragma unroll
    for (int n = 0; n < NT; ++n) {
      const f16x8 b = *(const f16x8*)((const _Float16*)Wt +
                        (size_t)(n * 16 + lrow) * K + kk + lk);
      acc[n] = __builtin_amdgcn_mfma_f32_16x16x32_f16(a, b, acc[n], 0, 0, 0);
    }
  }
  const int orow = row0 + w * 16 + (l >> 4) * 4;
#pragma unroll
  for (int n = 0; n < NT; ++n) {
#pragma unroll
    for (int j = 0; j < 4; ++j) {
      const int gr = orow + j;
      if (gr < N) Y[(size_t)gr * 64 + n * 16 + lrow] = __float2half(acc[n][j]);
    }
  }
#pragma unroll
  for (int j = 0; j < 4; ++j) {
    float ps = 0.f, pd = 0.f;
#pragma unroll
    for (int n = 0; n < NT; ++n) {
      ps += acc[n][j] * as[n * 16 + lrow];
      pd += acc[n][j] * ad[n * 16 + lrow];
    }
#pragma unroll
    for (int o = 1; o <= 8; o <<= 1) {
      ps += __shfl_xor(ps, o);
      pd += __shfl_xor(pd, o);
    }
    if (lrow == 0) {
      const int gr = orow + j;
      if (gr < N) { es[gr] = ps * LOG2E; ed[gr] = pd * LOG2E; }
    }
  }
}

// ---------------- layer-1 gather: 4 edges/wave, 16 lanes x 8ch each ---------
__global__ __launch_bounds__(256) void gather_h8(const __half* __restrict__ xl,
    const float* __restrict__ es, const float* __restrict__ ed,
    const int* __restrict__ rowptr, const int* __restrict__ csr,
    const float* __restrict__ bias, __half* __restrict__ hout, int N) {
  const int wave = threadIdx.x >> 6, lane = threadIdx.x & 63;
  const int n = blockIdx.x * 4 + wave;
  if (n >= N) return;
  const int sub = lane >> 4;       // 0..3
  const int sl  = lane & 15;       // channels 8sl..8sl+7
  const int c0  = sl * 8;
  const int h   = sl >> 1;
  const float edv = ed[n * 8 + h];
  const int start = (n == 0) ? 0 : rowptr[n - 1];
  const int end   = rowptr[n];
  union U16 { uint4 u; __half2 h2[4]; };

  float acc[8] = {0.f, 0.f, 0.f, 0.f, 0.f, 0.f, 0.f, 0.f};
  float ssum = 0.f;
  if (sub == 0) {    // self loop
    const float ee = exp2f(lrelu(es[n * 8 + h] + edv));
    U16 r; r.u = *(const uint4*)&xl[(size_t)n * 128 + c0];
#pragma unroll
    for (int q = 0; q < 4; ++q) {
      const float2 f = __half22float2(r.h2[q]);
      acc[2 * q] += ee * f.x; acc[2 * q + 1] += ee * f.y;
    }
    ssum = ee;
  }
  int j = start + sub;
  for (; j + 4 < end; j += 8) {    // 2 edges per sub per trip (8/wave)
    const int s0 = csr[j], s1 = csr[j + 4];
    const float e0 = es[s0 * 8 + h], e1 = es[s1 * 8 + h];
    U16 r0, r1;
    r0.u = *(const uint4*)&xl[(size_t)s0 * 128 + c0];
    r1.u = *(const uint4*)&xl[(size_t)s1 * 128 + c0];
    const float ee0 = exp2f(lrelu(e0 + edv));
    const float ee1 = exp2f(lrelu(e1 + edv));
#pragma unroll
    for (int q = 0; q < 4; ++q) {
      const float2 f0 = __half22float2(r0.h2[q]);
      const float2 f1 = __half22float2(r1.h2[q]);
      acc[2 * q]     += ee0 * f0.x + ee1 * f1.x;
      acc[2 * q + 1] += ee0 * f0.y + ee1 * f1.y;
    }
    ssum += ee0 + ee1;
  }
  for (; j < end; j += 4) {
    const int src = csr[j];
    const float ee = exp2f(lrelu(es[src * 8 + h] + edv));
    U16 r; r.u = *(const uint4*)&xl[(size_t)src * 128 + c0];
#pragma unroll
    for (int q = 0; q < 4; ++q) {
      const float2 f = __half22float2(r.h2[q]);
      acc[2 * q] += ee * f.x; acc[2 * q + 1] += ee * f.y;
    }
    ssum += ee;
  }
#pragma unroll
  for (int o = 16; o <= 32; o <<= 1) {
#pragma unroll
    for (int q = 0; q < 8; ++q) acc[q] += __shfl_xor(acc[q], o);
    ssum += __shfl_xor(ssum, o);
  }
  if (sub == 0) {
    const float inv = 1.f / (ssum + 1e-16f);
    const float4 b0 = *(const float4*)&bias[c0];
    const float4 b1 = *(const float4*)&bias[c0 + 4];
    float v[8];
    v[0] = acc[0] * inv + b0.x; v[1] = acc[1] * inv + b0.y;
    v[2] = acc[2] * inv + b0.z; v[3] = acc[3] * inv + b0.w;
    v[4] = acc[4] * inv + b1.x; v[5] = acc[5] * inv + b1.y;
    v[6] = acc[6] * inv + b1.z; v[7] = acc[7] * inv + b1.w;
#pragma unroll
    for (int q = 0; q < 8; ++q) v[q] = v[q] > 0.f ? v[q] : __expf(v[q]) - 1.f;
    U16 o;
#pragma unroll
    for (int q = 0; q < 4; ++q) o.h2[q] = __floats2half2_rn(v[2 * q], v[2 * q + 1]);
    *(uint4*)&hout[(size_t)n * 128 + c0] = o.u;
  }
}

// ---------------- layer-2 gather: 4 edges/wave, 16 lanes x 4ch each ---------
__global__ __launch_bounds__(256) void gather_h1(const __half* __restrict__ xl2,
    const float* __restrict__ es, const float* __restrict__ ed,
    const int* __restrict__ rowptr, const int* __restrict__ csr,
    const float* __restrict__ bias, float* __restrict__ vout, int N) {
  const int wave = threadIdx.x >> 6, lane = threadIdx.x & 63;
  const int n = blockIdx.x * 4 + wave;
  if (n >= N) return;
  const int sub = lane >> 4;       // 0..3
  const int sl  = lane & 15;       // channels 4sl..4sl+3
  const int c0  = sl * 4;
  const float edv = ed[n];
  const int start = (n == 0) ? 0 : rowptr[n - 1];
  const int end   = rowptr[n];
  union U8 { uint2 u; __half2 h2[2]; };

  float4 acc = make_float4(0.f, 0.f, 0.f, 0.f);
  float ssum = 0.f;
  if (sub == 0) {    // self loop
    const float ee = exp2f(lrelu(es[n] + edv));
    U8 r; r.u = *(const uint2*)&xl2[(size_t)n * 64 + c0];
    const float2 f0 = __half22float2(r.h2[0]), f1 = __half22float2(r.h2[1]);
    acc.x = ee * f0.x; acc.y = ee * f0.y; acc.z = ee * f1.x; acc.w = ee * f1.y;
    ssum = ee;
  }
  int j = start + sub;
  for (; j + 4 < end; j += 8) {    // 2 edges per sub per trip (8/wave)
    const int s0 = csr[j], s1 = csr[j + 4];
    const float e0 = es[s0], e1 = es[s1];
    U8 r0, r1;
    r0.u = *(const uint2*)&xl2[(size_t)s0 * 64 + c0];
    r1.u = *(const uint2*)&xl2[(size_t)s1 * 64 + c0];
    const float ee0 = exp2f(lrelu(e0 + edv));
    const float ee1 = exp2f(lrelu(e1 + edv));
    {
      const float2 f0 = __half22float2(r0.h2[0]), f1 = __half22float2(r0.h2[1]);
      acc.x += ee0 * f0.x; acc.y += ee0 * f0.y;
      acc.z += ee0 * f1.x; acc.w += ee0 * f1.y;
    }
    {
      const float2 f0 = __half22float2(r1.h2[0]), f1 = __half22float2(r1.h2[1]);
      acc.x += ee1 * f0.x; acc.y += ee1 * f0.y;
      acc.z += ee1 * f1.x; acc.w += ee1 * f1.y;
    }
    ssum += ee0 + ee1;
  }
  for (; j < end; j += 4) {
    const int src = csr[j];
    const float ee = exp2f(lrelu(es[src] + edv));
    U8 r; r.u = *(const uint2*)&xl2[(size_t)src * 64 + c0];
    const float2 f0 = __half22float2(r.h2[0]), f1 = __half22float2(r.h2[1]);
    acc.x += ee * f0.x; acc.y += ee * f0.y;
    acc.z += ee * f1.x; acc.w += ee * f1.y; ssum += ee;
  }
#pragma unroll
  for (int o = 16; o <= 32; o <<= 1) {
    acc.x += __shfl_xor(acc.x, o); acc.y += __shfl_xor(acc.y, o);
    acc.z += __shfl_xor(acc.z, o); acc.w += __shfl_xor(acc.w, o);
    ssum  += __shfl_xor(ssum, o);
  }
  if (sub == 0) {
    const float inv = 1.f / (ssum + 1e-16f);
    const float4 b4 = *(const float4*)&bias[c0];
    float4 o;
    o.x = acc.x * inv + b4.x; o.y = acc.y * inv + b4.y;
    o.z = acc.z * inv + b4.z; o.w = acc.w * inv + b4.w;
    *(float4*)&vout[(size_t)n * 64 + c0] = o;
  }
}

// ---------------- segmented mean pool: 1 block per graph --------------------
__global__ __launch_bounds__(256) void pool_seg(const float* __restrict__ v,
    const int* __restrict__ batch, float* __restrict__ out, int N) {
  const int g = blockIdx.x;
  const int t = threadIdx.x;
  int lo = 0, hi = N;
  while (lo < hi) { const int m = (lo + hi) >> 1; if (batch[m] < g) lo = m + 1; else hi = m; }
  const int start = lo;
  hi = N;
  while (lo < hi) { const int m = (lo + hi) >> 1; if (batch[m] <= g) lo = m + 1; else hi = m; }
  const int end = lo;

  const int c = t & 63, rg = t >> 6;
  float s = 0.f;
  for (int r = start + rg; r < end; r += 4) s += v[(size_t)r * 64 + c];
  __shared__ float sm[256];
  sm[t] = s;
  __syncthreads();
  if (t < 64) {
    const float tot = sm[t] + sm[t + 64] + sm[t + 128] + sm[t + 192];
    out[g * 64 + t] = tot / fmaxf((float)(end - start), 1.f);
  }
}

extern "C" void kernel_launch(void* const* d_in, const int* in_sizes, int n_in,
                              void* d_out, int out_size, void* d_ws, size_t ws_size,
                              hipStream_t stream) {
  const float* x   = (const float*)d_in[0];
  const float* W1  = (const float*)d_in[1];
  const float* as1 = (const float*)d_in[2];
  const float* ad1 = (const float*)d_in[3];
  const float* b1  = (const float*)d_in[4];
  const float* W2  = (const float*)d_in[5];
  const float* as2 = (const float*)d_in[6];
  const float* ad2 = (const float*)d_in[7];
  const float* b2  = (const float*)d_in[8];
  const int* ei    = (const int*)d_in[9];
  const int* batch = (const int*)d_in[10];
  float* out = (float*)d_out;
  const int N = in_sizes[10];      // 100000
  const int E = in_sizes[9] / 2;   // 1600000
  const int G = out_size / 64;     // 256 graphs
  const int BH = NBUCK * NBLKB;    // 131072
  const int nbCsr = (N + 511) / 512;      // 196
  const int nbGemm1 = (N + 127) / 128;    // 782

  // workspace layout (bytes), with reuse:
  char* ws = (char*)d_ws;
  __half* xl  = (__half*)ws;                         // [N*128] f16
  __half* h   = (__half*)(ws + (size_t)N * 256);     // [N*128] f16
  __half* xl2 = xl;                                  // [N*64] f16 (xl dead)
  float* vbuf = (float*)(ws + (size_t)N * 256);      // [N*64] f32 (h dead)
  float* es1  = (float*)(ws + (size_t)N * 512);      // [N*8]
  float* ed1  = es1 + (size_t)N * 8;                 // [N*8]
  float* es2  = es1;                                 // [N]
  float* ed2  = es1 + N;                             // [N]
  int* rowptr = (int*)(ed1 + (size_t)N * 8);         // [N]
  int* csr    = rowptr + N;                          // [E]
  int* eb     = csr + E;                             // [E] packed (src<<9|dstlo)
  int* bh     = eb + E;                              // [131072]
  int* ctot   = bh + BH;                             // [128]
  __half* Wt1 = (__half*)((((uintptr_t)(ctot + 128)) + 31) & ~(uintptr_t)31); // [128*128]
  __half* Wt2 = Wt1 + 128 * 128;                     // [64*128]

  // ---- CSR build (hist fused with W convert) ----
  hist_conv<<<NBLKB + 24, 1024, 0, stream>>>(ei, E, bh, W1, W2, Wt1, Wt2);
  scanA<<<BH / 1024, 256, 0, stream>>>(bh, ctot, BH);
  scanC<<<BH / 256, 256, 0, stream>>>(bh, ctot, BH / 1024, BH);
  bucket_scatter<<<NBLKB, 1024, 0, stream>>>(ei, E, bh, eb);

  // ---- csr finalize || layer-1 GEMM (fused, concurrent) ----
  csrb_gemm1<<<nbCsr + nbGemm1, 512, 0, stream>>>(eb, bh, E, rowptr, csr, nbCsr,
      x, Wt1, xl, as1, ad1, es1, ed1, N);
  gather_h8<<<(N + 3) / 4, 256, 0, stream>>>(xl, es1, ed1, rowptr, csr, b1, h, N);

  // ---- layer 2 ----
  gemm2<<<(N + 63) / 64, 256, 0, stream>>>(h, Wt2, xl2, as2, ad2, es2, ed2, N);
  gather_h1<<<(N + 3) / 4, 256, 0, stream>>>(xl2, es2, ed2, rowptr, csr, b2, vbuf, N);

  // ---- global mean pool (segmented, no atomics) ----
  pool_seg<<<G, 256, 0, stream>>>(vbuf, batch, out, N);
}

// Round 12
// 265.980 us; speedup vs baseline: 1.2041x; 1.0132x over previous
//
#include <hip/hip_runtime.h>
#include <hip/hip_fp16.h>

// GAT 2-layer forward, MI355X. N=100000, E=1.6M (+N self-loops), Fin=128,
// H=8, C=16 (H*C=128), Fout=64, 256 graphs.
//
// Round 12: (a) gather inner loops in v_fma_mix form (f16 src -> f32 fma,
// no standalone cvts); (b) gather_h1 widened to 8 lanes x 8ch, 8 edges/wave;
// (c) gemm2 at BM=128/512thr. Structure otherwise = r11.

#define LRELU_SLOPE 0.2f
#define NBLKB 512          // bucketing blocks
#define NBUCK 256          // buckets (dst>>9, N<=131072)
#define LOG2E 1.4426950408889634f

__device__ __forceinline__ float lrelu(float x) { return x > 0.f ? x : LRELU_SLOPE * x; }

typedef _Float16 f16x8 __attribute__((ext_vector_type(8)));
typedef float f32x4 __attribute__((ext_vector_type(4)));

// ---------------- K1: bucket histogram + W1/W2 convert-transpose ------------
__global__ __launch_bounds__(1024) void hist_conv(const int* __restrict__ ei, int E,
    int* __restrict__ bh, const float* __restrict__ W1, const float* __restrict__ W2,
    __half* __restrict__ Wt1, __half* __restrict__ Wt2) {
  const int t = threadIdx.x;
  if (blockIdx.x < NBLKB) {
    __shared__ int hist[NBUCK];
    if (t < NBUCK) hist[t] = 0;
    __syncthreads();
    const int chunk = (E + NBLKB - 1) / NBLKB;
    const int s0 = blockIdx.x * chunk;
    const int s1 = min(E, s0 + chunk);
    for (int e = s0 + t; e < s1; e += 1024) atomicAdd(&hist[ei[E + e] >> 9], 1);
    __syncthreads();
    if (t < NBUCK) bh[t * NBLKB + blockIdx.x] = hist[t];
  } else {
    const int i = (blockIdx.x - NBLKB) * 1024 + t;
    if (i < 128 * 128) {
      const int k = i >> 7, m = i & 127;
      Wt1[m * 128 + k] = __float2half(W1[i]);
    } else if (i < 128 * 128 + 128 * 64) {
      const int j = i - 128 * 128;
      const int k = j >> 6, m = j & 63;
      Wt2[m * 128 + k] = __float2half(W2[j]);
    }
  }
}

// ---------------- scans ------------------------------------------------------
__global__ __launch_bounds__(256) void scanA(int* __restrict__ a, int* __restrict__ ctot, int N) {
  __shared__ int sm[256];
  const int base = blockIdx.x * 1024;
  const int t = threadIdx.x;
  int v[4], s = 0;
#pragma unroll
  for (int i = 0; i < 4; ++i) {
    const int idx = base + t * 4 + i;
    v[i] = (idx < N) ? a[idx] : 0;
    s += v[i];
  }
  sm[t] = s;
  __syncthreads();
  for (int o = 1; o < 256; o <<= 1) {
    const int x = (t >= o) ? sm[t - o] : 0;
    __syncthreads();
    sm[t] += x;
    __syncthreads();
  }
  if (t == 255) ctot[blockIdx.x] = sm[255];
  int run = sm[t] - s;
#pragma unroll
  for (int i = 0; i < 4; ++i) {
    const int idx = base + t * 4 + i;
    if (idx < N) a[idx] = run;
    run += v[i];
  }
}

__global__ __launch_bounds__(256) void scanC(int* __restrict__ a,
    const int* __restrict__ ctot, int NCH, int Ntot) {
  __shared__ int sc[128];
  const int t = threadIdx.x;
  if (t < 128) sc[t] = (t < NCH) ? ctot[t] : 0;
  __syncthreads();
  for (int o = 1; o < 128; o <<= 1) {
    int x = 0;
    if (t < 128 && t >= o) x = sc[t - o];
    __syncthreads();
    if (t < 128) sc[t] += x;
    __syncthreads();
  }
  const int i = blockIdx.x * 256 + t;
  if (i < Ntot) {
    const int c = i >> 10;
    a[i] += (c == 0) ? 0 : sc[c - 1];
  }
}

// ---------------- K3: scatter into bucket-grouped packed records ------------
__global__ __launch_bounds__(1024) void bucket_scatter(const int* __restrict__ ei, int E,
    const int* __restrict__ bh, int* __restrict__ eb) {
  __shared__ int offs[NBUCK];
  const int t = threadIdx.x;
  if (t < NBUCK) offs[t] = bh[t * NBLKB + blockIdx.x];
  __syncthreads();
  const int chunk = (E + NBLKB - 1) / NBLKB;
  const int s0 = blockIdx.x * chunk;
  const int s1 = min(E, s0 + chunk);
  for (int e = s0 + t; e < s1; e += 1024) {
    const int s = ei[e], d = ei[E + e];
    const int pos = atomicAdd(&offs[d >> 9], 1);
    eb[pos] = (s << 9) | (d & 511);
  }
}

// ---------------- K4 fused: csr_bucket (blocks < nbCsr) | gemm1 (rest) ------
__global__ __launch_bounds__(512) void csrb_gemm1(
    const int* __restrict__ eb, const int* __restrict__ bh, int E,
    int* __restrict__ rowptr, int* __restrict__ csr, int nbCsr,
    const float* __restrict__ X, const __half* __restrict__ Wt,
    __half* __restrict__ Y, const float* __restrict__ as,
    const float* __restrict__ ad, float* __restrict__ es, float* __restrict__ ed,
    int N) {
  __shared__ union U {
    struct { int deg[512]; int sm[512]; } c;
    _Float16 xl[128 * 136];
  } u;
  const int t = threadIdx.x;

  if (blockIdx.x < nbCsr) {
    const int bucket = blockIdx.x;
    const int bstart = bh[bucket * NBLKB];
    const int bend = (bucket + 1 < NBUCK) ? bh[(bucket + 1) * NBLKB] : E;
    const int n0 = bucket << 9;
    u.c.deg[t] = 0;
    __syncthreads();
    for (int j = bstart + t; j < bend; j += 512) atomicAdd(&u.c.deg[eb[j] & 511], 1);
    __syncthreads();
    const int v = u.c.deg[t];
    u.c.sm[t] = v;
    __syncthreads();
    for (int o = 1; o < 512; o <<= 1) {
      const int x = (t >= o) ? u.c.sm[t - o] : 0;
      __syncthreads();
      u.c.sm[t] += x;
      __syncthreads();
    }
    if (n0 + t < N) rowptr[n0 + t] = bstart + u.c.sm[t];
    u.c.deg[t] = bstart + u.c.sm[t] - v;
    __syncthreads();
    for (int j = bstart + t; j < bend; j += 512) {
      const int e = eb[j];
      const int pos = atomicAdd(&u.c.deg[e & 511], 1);
      csr[pos] = e >> 9;
    }
  } else {
    constexpr int K = 128, LP = 136, NT = 8;
    const int row0 = (blockIdx.x - nbCsr) * 128;
    for (int i = t; i < 128 * (K / 4); i += 512) {
      const int r = i / (K / 4), c4 = (i % (K / 4)) * 4;
      int gr = row0 + r; if (gr >= N) gr = N - 1;
      const float4 vv = *(const float4*)(X + (size_t)gr * K + c4);
      _Float16* d = &u.xl[r * LP + c4];
      d[0] = (_Float16)vv.x; d[1] = (_Float16)vv.y;
      d[2] = (_Float16)vv.z; d[3] = (_Float16)vv.w;
    }
    __syncthreads();

    const int w = t >> 6, l = t & 63;
    const int lrow = l & 15, lk = (l >> 4) * 8;
    f32x4 acc[NT];
#pragma unroll
    for (int n = 0; n < NT; ++n) acc[n] = (f32x4){0.f, 0.f, 0.f, 0.f};
#pragma unroll
    for (int kk = 0; kk < K; kk += 32) {
      const f16x8 a = *(const f16x8*)&u.xl[(w * 16 + lrow) * LP + kk + lk];
#pragma unroll
      for (int n = 0; n < NT; ++n) {
        const f16x8 b = *(const f16x8*)((const _Float16*)Wt +
                          (size_t)(n * 16 + lrow) * K + kk + lk);
        acc[n] = __builtin_amdgcn_mfma_f32_16x16x32_f16(a, b, acc[n], 0, 0, 0);
      }
    }
    const int orow = row0 + w * 16 + (l >> 4) * 4;
#pragma unroll
    for (int n = 0; n < NT; ++n) {
#pragma unroll
      for (int j = 0; j < 4; ++j) {
        const int gr = orow + j;
        if (gr < N) Y[(size_t)gr * 128 + n * 16 + lrow] = __float2half(acc[n][j]);
      }
    }
#pragma unroll
    for (int n = 0; n < NT; ++n) {
#pragma unroll
      for (int j = 0; j < 4; ++j) {
        float ps = acc[n][j] * as[n * 16 + lrow];
        float pd = acc[n][j] * ad[n * 16 + lrow];
#pragma unroll
        for (int o = 1; o <= 8; o <<= 1) {
          ps += __shfl_xor(ps, o);
          pd += __shfl_xor(pd, o);
        }
        if (lrow == n) {
          const int gr = orow + j;
          if (gr < N) { es[gr * 8 + n] = ps * LOG2E; ed[gr * 8 + n] = pd * LOG2E; }
        }
      }
    }
  }
}

// ---------------- gemm2 (M=64, H=1), BM=128, 512 threads --------------------
__global__ __launch_bounds__(512) void gemm2(const __half* __restrict__ X,
    const __half* __restrict__ Wt, __half* __restrict__ Y,
    const float* __restrict__ as, const float* __restrict__ ad,
    float* __restrict__ es, float* __restrict__ ed, int N) {
  constexpr int K = 128, BM = 128, LP = 136, NT = 4;
  __shared__ _Float16 Xl[BM * LP];
  const int tid = threadIdx.x;
  const int row0 = blockIdx.x * BM;
  for (int i = tid; i < BM * (K / 8); i += 512) {
    const int r = i / (K / 8), c8 = (i % (K / 8)) * 8;
    int gr = row0 + r; if (gr >= N) gr = N - 1;
    const f16x8 v = *(const f16x8*)((const _Float16*)X + (size_t)gr * K + c8);
    *(f16x8*)&Xl[r * LP + c8] = v;
  }
  __syncthreads();
  const int w = tid >> 6, l = tid & 63;
  const int lrow = l & 15, lk = (l >> 4) * 8;
  f32x4 acc[NT];
#pragma unroll
  for (int n = 0; n < NT; ++n) acc[n] = (f32x4){0.f, 0.f, 0.f, 0.f};
#pragma unroll
  for (int kk = 0; kk < K; kk += 32) {
    const f16x8 a = *(const f16x8*)&Xl[(w * 16 + lrow) * LP + kk + lk];
#pragma unroll
    for (int n = 0; n < NT; ++n) {
      const f16x8 b = *(const f16x8*)((const _Float16*)Wt +
                        (size_t)(n * 16 + lrow) * K + kk + lk);
      acc[n] = __builtin_amdgcn_mfma_f32_16x16x32_f16(a, b, acc[n], 0, 0, 0);
    }
  }
  const int orow = row0 + w * 16 + (l >> 4) * 4;
#pragma unroll
  for (int n = 0; n < NT; ++n) {
#pragma unroll
    for (int j = 0; j < 4; ++j) {
      const int gr = orow + j;
      if (gr < N) Y[(size_t)gr * 64 + n * 16 + lrow] = __float2half(acc[n][j]);
    }
  }
#pragma unroll
  for (int j = 0; j < 4; ++j) {
    float ps = 0.f, pd = 0.f;
#pragma unroll
    for (int n = 0; n < NT; ++n) {
      ps += acc[n][j] * as[n * 16 + lrow];
      pd += acc[n][j] * ad[n * 16 + lrow];
    }
#pragma unroll
    for (int o = 1; o <= 8; o <<= 1) {
      ps += __shfl_xor(ps, o);
      pd += __shfl_xor(pd, o);
    }
    if (lrow == 0) {
      const int gr = orow + j;
      if (gr < N) { es[gr] = ps * LOG2E; ed[gr] = pd * LOG2E; }
    }
  }
}

// ---------------- layer-1 gather: 4 edges/wave, 16 lanes x 8ch (fma_mix) ----
__global__ __launch_bounds__(256) void gather_h8(const __half* __restrict__ xl,
    const float* __restrict__ es, const float* __restrict__ ed,
    const int* __restrict__ rowptr, const int* __restrict__ csr,
    const float* __restrict__ bias, __half* __restrict__ hout, int N) {
  const int wave = threadIdx.x >> 6, lane = threadIdx.x & 63;
  const int n = blockIdx.x * 4 + wave;
  if (n >= N) return;
  const int sub = lane >> 4;       // 0..3
  const int sl  = lane & 15;       // channels 8sl..8sl+7
  const int c0  = sl * 8;
  const int h   = sl >> 1;
  const float edv = ed[n * 8 + h];
  const int start = (n == 0) ? 0 : rowptr[n - 1];
  const int end   = rowptr[n];
  union U16 { uint4 u; __half2 h2[4]; };

  float acc[8] = {0.f, 0.f, 0.f, 0.f, 0.f, 0.f, 0.f, 0.f};
  float ssum = 0.f;
  if (sub == 0) {    // self loop
    const float ee = exp2f(lrelu(es[n * 8 + h] + edv));
    U16 r; r.u = *(const uint4*)&xl[(size_t)n * 128 + c0];
#pragma unroll
    for (int q = 0; q < 4; ++q) {
      acc[2 * q]     = fmaf(ee, __low2float(r.h2[q]),  acc[2 * q]);
      acc[2 * q + 1] = fmaf(ee, __high2float(r.h2[q]), acc[2 * q + 1]);
    }
    ssum = ee;
  }
  int j = start + sub;
  for (; j + 4 < end; j += 8) {    // 2 edges per sub per trip (8/wave)
    const int s0 = csr[j], s1 = csr[j + 4];
    const float e0 = es[s0 * 8 + h], e1 = es[s1 * 8 + h];
    U16 r0, r1;
    r0.u = *(const uint4*)&xl[(size_t)s0 * 128 + c0];
    r1.u = *(const uint4*)&xl[(size_t)s1 * 128 + c0];
    const float ee0 = exp2f(lrelu(e0 + edv));
    const float ee1 = exp2f(lrelu(e1 + edv));
#pragma unroll
    for (int q = 0; q < 4; ++q) {
      acc[2 * q]     = fmaf(ee0, __low2float(r0.h2[q]),  acc[2 * q]);
      acc[2 * q]     = fmaf(ee1, __low2float(r1.h2[q]),  acc[2 * q]);
      acc[2 * q + 1] = fmaf(ee0, __high2float(r0.h2[q]), acc[2 * q + 1]);
      acc[2 * q + 1] = fmaf(ee1, __high2float(r1.h2[q]), acc[2 * q + 1]);
    }
    ssum += ee0 + ee1;
  }
  for (; j < end; j += 4) {
    const int src = csr[j];
    const float ee = exp2f(lrelu(es[src * 8 + h] + edv));
    U16 r; r.u = *(const uint4*)&xl[(size_t)src * 128 + c0];
#pragma unroll
    for (int q = 0; q < 4; ++q) {
      acc[2 * q]     = fmaf(ee, __low2float(r.h2[q]),  acc[2 * q]);
      acc[2 * q + 1] = fmaf(ee, __high2float(r.h2[q]), acc[2 * q + 1]);
    }
    ssum += ee;
  }
#pragma unroll
  for (int o = 16; o <= 32; o <<= 1) {
#pragma unroll
    for (int q = 0; q < 8; ++q) acc[q] += __shfl_xor(acc[q], o);
    ssum += __shfl_xor(ssum, o);
  }
  if (sub == 0) {
    const float inv = 1.f / (ssum + 1e-16f);
    const float4 b0 = *(const float4*)&bias[c0];
    const float4 b1 = *(const float4*)&bias[c0 + 4];
    float v[8];
    v[0] = acc[0] * inv + b0.x; v[1] = acc[1] * inv + b0.y;
    v[2] = acc[2] * inv + b0.z; v[3] = acc[3] * inv + b0.w;
    v[4] = acc[4] * inv + b1.x; v[5] = acc[5] * inv + b1.y;
    v[6] = acc[6] * inv + b1.z; v[7] = acc[7] * inv + b1.w;
#pragma unroll
    for (int q = 0; q < 8; ++q) v[q] = v[q] > 0.f ? v[q] : __expf(v[q]) - 1.f;
    U16 o;
#pragma unroll
    for (int q = 0; q < 4; ++q) o.h2[q] = __floats2half2_rn(v[2 * q], v[2 * q + 1]);
    *(uint4*)&hout[(size_t)n * 128 + c0] = o.u;
  }
}

// ---------------- layer-2 gather: 8 edges/wave, 8 lanes x 8ch (fma_mix) -----
__global__ __launch_bounds__(256) void gather_h1(const __half* __restrict__ xl2,
    const float* __restrict__ es, const float* __restrict__ ed,
    const int* __restrict__ rowptr, const int* __restrict__ csr,
    const float* __restrict__ bias, float* __restrict__ vout, int N) {
  const int wave = threadIdx.x >> 6, lane = threadIdx.x & 63;
  const int n = blockIdx.x * 4 + wave;
  if (n >= N) return;
  const int sub = lane >> 3;       // 0..7
  const int sl  = lane & 7;        // channels 8sl..8sl+7
  const int c0  = sl * 8;
  const float edv = ed[n];
  const int start = (n == 0) ? 0 : rowptr[n - 1];
  const int end   = rowptr[n];
  union U16 { uint4 u; __half2 h2[4]; };

  float acc[8] = {0.f, 0.f, 0.f, 0.f, 0.f, 0.f, 0.f, 0.f};
  float ssum = 0.f;
  if (sub == 0) {    // self loop
    const float ee = exp2f(lrelu(es[n] + edv));
    U16 r; r.u = *(const uint4*)&xl2[(size_t)n * 64 + c0];
#pragma unroll
    for (int q = 0; q < 4; ++q) {
      acc[2 * q]     = fmaf(ee, __low2float(r.h2[q]),  acc[2 * q]);
      acc[2 * q + 1] = fmaf(ee, __high2float(r.h2[q]), acc[2 * q + 1]);
    }
    ssum = ee;
  }
  int j = start + sub;
  for (; j + 8 < end; j += 16) {   // 2 edges per sub per trip (16/wave)
    const int s0 = csr[j], s1 = csr[j + 8];
    const float e0 = es[s0], e1 = es[s1];
    U16 r0, r1;
    r0.u = *(const uint4*)&xl2[(size_t)s0 * 64 + c0];
    r1.u = *(const uint4*)&xl2[(size_t)s1 * 64 + c0];
    const float ee0 = exp2f(lrelu(e0 + edv));
    const float ee1 = exp2f(lrelu(e1 + edv));
#pragma unroll
    for (int q = 0; q < 4; ++q) {
      acc[2 * q]     = fmaf(ee0, __low2float(r0.h2[q]),  acc[2 * q]);
      acc[2 * q]     = fmaf(ee1, __low2float(r1.h2[q]),  acc[2 * q]);
      acc[2 * q + 1] = fmaf(ee0, __high2float(r0.h2[q]), acc[2 * q + 1]);
      acc[2 * q + 1] = fmaf(ee1, __high2float(r1.h2[q]), acc[2 * q + 1]);
    }
    ssum += ee0 + ee1;
  }
  for (; j < end; j += 8) {
    const int src = csr[j];
    const float ee = exp2f(lrelu(es[src] + edv));
    U16 r; r.u = *(const uint4*)&xl2[(size_t)src * 64 + c0];
#pragma unroll
    for (int q = 0; q < 4; ++q) {
      acc[2 * q]     = fmaf(ee, __low2float(r.h2[q]),  acc[2 * q]);
      acc[2 * q + 1] = fmaf(ee, __high2float(r.h2[q]), acc[2 * q + 1]);
    }
    ssum += ee;
  }
#pragma unroll
  for (int o = 8; o <= 32; o <<= 1) {
#pragma unroll
    for (int q = 0; q < 8; ++q) acc[q] += __shfl_xor(acc[q], o);
    ssum += __shfl_xor(ssum, o);
  }
  if (sub == 0) {
    const float inv = 1.f / (ssum + 1e-16f);
    const float4 b0 = *(const float4*)&bias[c0];
    const float4 b1 = *(const float4*)&bias[c0 + 4];
    float4 o0, o1;
    o0.x = acc[0] * inv + b0.x; o0.y = acc[1] * inv + b0.y;
    o0.z = acc[2] * inv + b0.z; o0.w = acc[3] * inv + b0.w;
    o1.x = acc[4] * inv + b1.x; o1.y = acc[5] * inv + b1.y;
    o1.z = acc[6] * inv + b1.z; o1.w = acc[7] * inv + b1.w;
    *(float4*)&vout[(size_t)n * 64 + c0] = o0;
    *(float4*)&vout[(size_t)n * 64 + c0 + 4] = o1;
  }
}

// ---------------- segmented mean pool: 1 block per graph --------------------
__global__ __launch_bounds__(256) void pool_seg(const float* __restrict__ v,
    const int* __restrict__ batch, float* __restrict__ out, int N) {
  const int g = blockIdx.x;
  const int t = threadIdx.x;
  int lo = 0, hi = N;
  while (lo < hi) { const int m = (lo + hi) >> 1; if (batch[m] < g) lo = m + 1; else hi = m; }
  const int start = lo;
  hi = N;
  while (lo < hi) { const int m = (lo + hi) >> 1; if (batch[m] <= g) lo = m + 1; else hi = m; }
  const int end = lo;

  const int c = t & 63, rg = t >> 6;
  float s = 0.f;
  for (int r = start + rg; r < end; r += 4) s += v[(size_t)r * 64 + c];
  __shared__ float sm[256];
  sm[t] = s;
  __syncthreads();
  if (t < 64) {
    const float tot = sm[t] + sm[t + 64] + sm[t + 128] + sm[t + 192];
    out[g * 64 + t] = tot / fmaxf((float)(end - start), 1.f);
  }
}

extern "C" void kernel_launch(void* const* d_in, const int* in_sizes, int n_in,
                              void* d_out, int out_size, void* d_ws, size_t ws_size,
                              hipStream_t stream) {
  const float* x   = (const float*)d_in[0];
  const float* W1  = (const float*)d_in[1];
  const float* as1 = (const float*)d_in[2];
  const float* ad1 = (const float*)d_in[3];
  const float* b1  = (const float*)d_in[4];
  const float* W2  = (const float*)d_in[5];
  const float* as2 = (const float*)d_in[6];
  const float* ad2 = (const float*)d_in[7];
  const float* b2  = (const float*)d_in[8];
  const int* ei    = (const int*)d_in[9];
  const int* batch = (const int*)d_in[10];
  float* out = (float*)d_out;
  const int N = in_sizes[10];      // 100000
  const int E = in_sizes[9] / 2;   // 1600000
  const int G = out_size / 64;     // 256 graphs
  const int BH = NBUCK * NBLKB;    // 131072
  const int nbCsr = (N + 511) / 512;      // 196
  const int nbGemm1 = (N + 127) / 128;    // 782

  // workspace layout (bytes), with reuse:
  char* ws = (char*)d_ws;
  __half* xl  = (__half*)ws;                         // [N*128] f16
  __half* h   = (__half*)(ws + (size_t)N * 256);     // [N*128] f16
  __half* xl2 = xl;                                  // [N*64] f16 (xl dead)
  float* vbuf = (float*)(ws + (size_t)N * 256);      // [N*64] f32 (h dead)
  float* es1  = (float*)(ws + (size_t)N * 512);      // [N*8]
  float* ed1  = es1 + (size_t)N * 8;                 // [N*8]
  float* es2  = es1;                                 // [N]
  float* ed2  = es1 + N;                             // [N]
  int* rowptr = (int*)(ed1 + (size_t)N * 8);         // [N]
  int* csr    = rowptr + N;                          // [E]
  int* eb     = csr + E;                             // [E] packed (src<<9|dstlo)
  int* bh     = eb + E;                              // [131072]
  int* ctot   = bh + BH;                             // [128]
  __half* Wt1 = (__half*)((((uintptr_t)(ctot + 128)) + 31) & ~(uintptr_t)31); // [128*128]
  __half* Wt2 = Wt1 + 128 * 128;                     // [64*128]

  // ---- CSR build (hist fused with W convert) ----
  hist_conv<<<NBLKB + 24, 1024, 0, stream>>>(ei, E, bh, W1, W2, Wt1, Wt2);
  scanA<<<BH / 1024, 256, 0, stream>>>(bh, ctot, BH);
  scanC<<<BH / 256, 256, 0, stream>>>(bh, ctot, BH / 1024, BH);
  bucket_scatter<<<NBLKB, 1024, 0, stream>>>(ei, E, bh, eb);

  // ---- csr finalize || layer-1 GEMM (fused, concurrent) ----
  csrb_gemm1<<<nbCsr + nbGemm1, 512, 0, stream>>>(eb, bh, E, rowptr, csr, nbCsr,
      x, Wt1, xl, as1, ad1, es1, ed1, N);
  gather_h8<<<(N + 3) / 4, 256, 0, stream>>>(xl, es1, ed1, rowptr, csr, b1, h, N);

  // ---- layer 2 ----
  gemm2<<<(N + 127) / 128, 512, 0, stream>>>(h, Wt2, xl2, as2, ad2, es2, ed2, N);
  gather_h1<<<(N + 3) / 4, 256, 0, stream>>>(xl2, es2, ed2, rowptr, csr, b2, vbuf, N);

  // ---- global mean pool (segmented, no atomics) ----
  pool_seg<<<G, 256, 0, stream>>>(vbuf, batch, out, N);
}